// Round 13
// baseline (83.817 us; speedup 1.0000x reference)
//
#include <hip/hip_runtime.h>
#include <hip/hip_bf16.h>

// Problem constants
#define B_   2
#define CH   32      // C
#define S_   1024    // H*W
#define DM   64      // D_MODEL
#define NH   4       // N_HEADS
#define DH   16      // D_HEAD
#define COUT 64
#define NBIN 128
#define NNODE 512
#define L2E  1.44269504088896f

#if __has_builtin(__builtin_amdgcn_exp2f)
#define EXP2F(x) __builtin_amdgcn_exp2f(x)
#else
#define EXP2F(x) exp2f(x)
#endif

// ws layout (floats):
//   [0 .. 255]        hdr[n][4] = {tmin, inv_u = 511/range, -, -}
//   [512 .. 131583]   T[n][h][512]  tables (64*4*512 = 131072 floats)
#define WS_HDR 0
#define WS_T   512

// ---------------------------------------------------------------------------
// K1: one block per (n,h): 256 blocks x 512 threads (2 waves/SIMD).
// Phase 1: redundant prep a_h; gather channel row (2 vals/thread); min/max;
//          histogram moments (count,S1,S2,S3 per bin) in LDS.
// Phase 2: each thread = one node tau_i (512 nodes) on [tmin,tmax]; evaluates
//          Phi(tau_i) = G/F via the 128-bin geometric-ladder sweep.
__global__ __launch_bounds__(512) void k_tab(const float* __restrict__ x,
                                             const float* __restrict__ embed_w,
                                             const float* __restrict__ q_w,
                                             const float* __restrict__ k_w,
                                             float* __restrict__ ws) {
    __shared__ __align__(16) float M[NBIN][4];
    __shared__ float sh[2 * 512];
    __shared__ float em_s[DM];
    __shared__ float a_s[NH];
    __shared__ float redmax[8], redmin[8];

    const int bid = blockIdx.x, tid = threadIdx.x;
    const int n = bid >> 2, h = bid & 3;
    const int b = n >> 5, c = n & 31;

    // zero moments + load embed
    for (int i = tid; i < NBIN * 4; i += 512) ((float*)M)[i] = 0.f;
    if (tid < DM) em_s[tid] = embed_w[tid];
    __syncthreads();

    // qv/kv partial sums (8-way split over e)
    {
        const int d = tid & 63, p = tid >> 6;     // p = 0..7
        float sq_ = 0.f, sk_ = 0.f;
        #pragma unroll
        for (int i = 0; i < 8; i++) {
            int e = p * 8 + i;
            float emv = em_s[e];
            sq_ = fmaf(q_w[d * DM + e], emv, sq_);
            sk_ = fmaf(k_w[d * DM + e], emv, sk_);
        }
        sh[tid] = sq_; sh[512 + tid] = sk_;
    }
    // gather this channel's 1024 values (2 per thread, strided, L2/L3-resident)
    const float* xp = x + b * (S_ * CH) + c;
    const float v0 = xp[(tid * 2 + 0) * CH];
    const float v1 = xp[(tid * 2 + 1) * CH];
    float lmax = fmaxf(v0, v1);
    float lmin = fminf(v0, v1);
    #pragma unroll
    for (int off = 32; off; off >>= 1) {
        lmax = fmaxf(lmax, __shfl_xor(lmax, off));
        lmin = fminf(lmin, __shfl_xor(lmin, off));
    }
    if ((tid & 63) == 0) { redmax[tid >> 6] = lmax; redmin[tid >> 6] = lmin; }
    __syncthreads();   // sh, red complete

    if (tid < NH) {
        float a = 0.f;
        #pragma unroll
        for (int i = 0; i < DH; i++) {
            int d = tid * DH + i;
            float qv = 0.f, kv = 0.f;
            #pragma unroll
            for (int j = 0; j < 8; j++) {
                qv += sh[d + 64 * j];
                kv += sh[512 + d + 64 * j];
            }
            a = fmaf(qv, kv, a);
        }
        a_s[tid] = a * 0.25f;   // 1/sqrt(16)
    }
    const float tmax = fmaxf(fmaxf(fmaxf(redmax[0], redmax[1]), fmaxf(redmax[2], redmax[3])),
                             fmaxf(fmaxf(redmax[4], redmax[5]), fmaxf(redmax[6], redmax[7])));
    const float tmin = fminf(fminf(fminf(redmin[0], redmin[1]), fminf(redmin[2], redmin[3])),
                             fminf(fminf(redmin[4], redmin[5]), fminf(redmin[6], redmin[7])));
    const float h_w  = (tmax - tmin) * (1.f / NBIN);
    const float b0   = tmin + 0.5f * h_w;
    const float binv = 1.f / h_w;

    // histogram moments (LDS atomics), 2 values per thread
    const float vs[2] = {v0, v1};
    #pragma unroll
    for (int i = 0; i < 2; i++) {
        float t = vs[i];
        int k = (int)((t - tmin) * binv);
        k = k > (NBIN - 1) ? (NBIN - 1) : k;
        float d = t - fmaf((float)k, h_w, b0);
        atomicAdd(&M[k][0], 1.f);
        atomicAdd(&M[k][1], d);
        atomicAdd(&M[k][2], d * d);
        atomicAdd(&M[k][3], d * d * d);
    }
    __syncthreads();   // M, a_s complete

    // ---- node sweep: tau = tmin + tid * (range/511) ----
    const float dtau = (tmax - tmin) * (1.f / (NNODE - 1));
    const float tau  = fmaf((float)tid, dtau, tmin);
    const float cc   = tau * a_s[h];
    const float C1 = cc;
    const float C2 = cc * cc * 0.5f;
    const float C3 = C2 * cc * (1.f / 3.f);
    const float c2e = cc * L2E;
    const float bLast = fmaf((float)(NBIN - 1), h_w, b0);
    const float nm2 = -fmaxf(cc * b0, cc * bLast) * L2E;
    const float r4 = EXP2F(c2e * (4.f * h_w));

    float F0 = 0.f, F1 = 0.f, F2 = 0.f, F3 = 0.f;
    float G0 = 0.f, G1 = 0.f, G2 = 0.f, G3 = 0.f;
    #pragma unroll
    for (int chnk = 0; chnk < 4; chnk++) {
        const float bfb = fmaf((float)(chnk * 32), h_w, b0);
        float E0 = EXP2F(fmaf(c2e, bfb,             nm2));
        float E1 = EXP2F(fmaf(c2e, bfb + h_w,       nm2));
        float E2 = EXP2F(fmaf(c2e, bfb + 2.f * h_w, nm2));
        float E3 = EXP2F(fmaf(c2e, bfb + 3.f * h_w, nm2));
        #pragma unroll
        for (int t = 0; t < 8; t++) {
            const int kb = chnk * 32 + t * 4;
            float4 m0 = *(const float4*)&M[kb + 0][0];
            float4 m1 = *(const float4*)&M[kb + 1][0];
            float4 m2 = *(const float4*)&M[kb + 2][0];
            float4 m3 = *(const float4*)&M[kb + 3][0];
            const float bf0 = fmaf((float)(t * 4), h_w, bfb);
            const float bf1 = bf0 + h_w;
            const float bf2 = bf0 + 2.f * h_w;
            const float bf3 = bf0 + 3.f * h_w;
            float PF0 = fmaf(C3, m0.w, fmaf(C2, m0.z, fmaf(C1, m0.y, m0.x)));
            float PF1 = fmaf(C3, m1.w, fmaf(C2, m1.z, fmaf(C1, m1.y, m1.x)));
            float PF2 = fmaf(C3, m2.w, fmaf(C2, m2.z, fmaf(C1, m2.y, m2.x)));
            float PF3 = fmaf(C3, m3.w, fmaf(C2, m3.z, fmaf(C1, m3.y, m3.x)));
            float QG0 = fmaf(C2, m0.w, fmaf(C1, m0.z, m0.y));
            float QG1 = fmaf(C2, m1.w, fmaf(C1, m1.z, m1.y));
            float QG2 = fmaf(C2, m2.w, fmaf(C1, m2.z, m2.y));
            float QG3 = fmaf(C2, m3.w, fmaf(C1, m3.z, m3.y));
            F0 = fmaf(E0, PF0, F0);
            F1 = fmaf(E1, PF1, F1);
            F2 = fmaf(E2, PF2, F2);
            F3 = fmaf(E3, PF3, F3);
            G0 = fmaf(E0, fmaf(bf0, PF0, QG0), G0);
            G1 = fmaf(E1, fmaf(bf1, PF1, QG1), G1);
            G2 = fmaf(E2, fmaf(bf2, PF2, QG2), G2);
            G3 = fmaf(E3, fmaf(bf3, PF3, QG3), G3);
            E0 *= r4; E1 *= r4; E2 *= r4; E3 *= r4;
        }
    }
    const float F = (F0 + F1) + (F2 + F3);
    const float G = (G0 + G1) + (G2 + G3);
    ws[WS_T + (n * NH + h) * NNODE + tid] = G / F;
    if (tid == 0) {
        ws[WS_HDR + n * 4 + 0] = tmin;
        ws[WS_HDR + n * 4 + 1] = (float)(NNODE - 1) / (tmax - tmin);
    }
}

// ---------------------------------------------------------------------------
// K2: 128 blocks = (b 2) x (s-tile 64 of 16); 256 threads.
// Redundant prep of vv -> ov[64][4]; per output: table-interp eval of
// w = Phi_{n,h}(x[b,s,c]); W2[h][s] = sum_c merge[c]*w; out = ov @ W2.
__global__ __launch_bounds__(256) void k_fin(const float* __restrict__ ws,
                                             const float* __restrict__ x,
                                             const float* __restrict__ embed_w,
                                             const float* __restrict__ v_w,
                                             const float* __restrict__ o_w,
                                             const float* __restrict__ merge_w,
                                             float* __restrict__ out) {
    __shared__ float em_s[DM];
    __shared__ float sh[256];
    __shared__ float vv[DM];
    __shared__ float ov_s[256];
    __shared__ float part[4][4][16];
    __shared__ float W2[4][16];
    __shared__ float msh[32];
    __shared__ float hdr_s[CH][2];
    const int bid = blockIdx.x, tid = threadIdx.x;
    const int b  = bid >> 6;
    const int s0 = (bid & 63) * 16;

    if (tid < DM) em_s[tid] = embed_w[tid];
    if (tid >= 64 && tid < 128) {
        int c = (tid - 64) >> 1, j = tid & 1;
        hdr_s[c][j] = ws[WS_HDR + (b * CH + c) * 4 + j];
    }
    if (tid >= 128 && tid < 160) msh[tid - 128] = merge_w[tid - 128];
    __syncthreads();
    {
        const int d = tid & 63, p = tid >> 6;
        float sv = 0.f;
        #pragma unroll
        for (int i = 0; i < 16; i++) {
            int e = p * 16 + i;
            sv = fmaf(v_w[d * DM + e], em_s[e], sv);
        }
        sh[tid] = sv;
    }
    __syncthreads();
    if (tid < DM) vv[tid] = (sh[tid] + sh[64 + tid]) + (sh[128 + tid] + sh[192 + tid]);
    __syncthreads();
    {
        const int o = tid & 63, hh0 = tid >> 6;
        float s = 0.f;
        #pragma unroll
        for (int i = 0; i < DH; i++)
            s = fmaf(o_w[o * DM + hh0 * DH + i], vv[hh0 * DH + i], s);
        ov_s[o * NH + hh0] = s;
    }

    const int sl = tid & 15, h = (tid >> 4) & 3, cg_ = tid >> 6;
    float acc = 0.f;
    #pragma unroll
    for (int k = 0; k < 8; k++) {
        const int c = cg_ * 8 + k;
        const int n = b * CH + c;
        const float ts = x[(b * S_ + s0 + sl) * CH + c];
        const float u0 = (ts - hdr_s[c][0]) * hdr_s[c][1];
        const float u  = fminf(fmaxf(u0, 0.f), (float)(NNODE - 1));
        int i = (int)u;
        i = i > (NNODE - 2) ? (NNODE - 2) : i;
        const float f = u - (float)i;
        const float* T = ws + WS_T + (n * NH + h) * NNODE;
        const float t0 = T[i], t1 = T[i + 1];
        const float w = fmaf(f, t1 - t0, t0);
        acc = fmaf(msh[c], w, acc);
    }
    part[cg_][h][sl] = acc;
    __syncthreads();   // ov_s and part complete
    if (tid < 64) {
        int hh = tid >> 4, ss = tid & 15;
        W2[hh][ss] = (part[0][hh][ss] + part[1][hh][ss]) +
                     (part[2][hh][ss] + part[3][hh][ss]);
    }
    __syncthreads();
    #pragma unroll
    for (int rep = 0; rep < 4; rep++) {
        int idx = rep * 256 + tid;
        int o2 = idx & 63, ss = idx >> 6;
        float r = 0.f;
        #pragma unroll
        for (int hh = 0; hh < NH; hh++)
            r = fmaf(ov_s[o2 * NH + hh], W2[hh][ss], r);
        out[(b * S_ + s0 + ss) * COUT + o2] = r;
    }
}

extern "C" void kernel_launch(void* const* d_in, const int* in_sizes, int n_in,
                              void* d_out, int out_size, void* d_ws, size_t ws_size,
                              hipStream_t stream) {
    const float* x       = (const float*)d_in[0];
    const float* embed_w = (const float*)d_in[1];
    const float* q_w     = (const float*)d_in[2];
    const float* k_w     = (const float*)d_in[3];
    const float* v_w     = (const float*)d_in[4];
    const float* o_w     = (const float*)d_in[5];
    const float* merge_w = (const float*)d_in[6];
    float* ws  = (float*)d_ws;
    float* out = (float*)d_out;

    k_tab<<<256, 512, 0, stream>>>(x, embed_w, q_w, k_w, ws);
    k_fin<<<B_ * 64, 256, 0, stream>>>(ws, x, embed_w, v_w, o_w, merge_w, out);
}

// Round 14
// 80.936 us; speedup vs baseline: 1.0356x; 1.0356x over previous
//
#include <hip/hip_runtime.h>
#include <hip/hip_bf16.h>
#include <hip/hip_fp16.h>

// Problem constants
#define B_   2
#define CH   32      // C
#define S_   1024    // H*W
#define DM   64      // D_MODEL
#define NH   4       // N_HEADS
#define DH   16      // D_HEAD
#define COUT 64
#define NBIN 128
#define NNODE 256
#define L2E  1.44269504088896f

#if __has_builtin(__builtin_amdgcn_exp2f)
#define EXP2F(x) __builtin_amdgcn_exp2f(x)
#else
#define EXP2F(x) exp2f(x)
#endif

// ws layout (floats):
//   [0 .. 255]       hdr[n][4] = {tmin, inv_u = 255/range, -, -}
//   [512 .. 66047]   T[n][h][256]  tables (64*4*256 = 65536 floats)
#define WS_HDR 0
#define WS_T   512

// ---------------------------------------------------------------------------
// K1: one block per (n,h): 256 blocks x 256 threads (R12 geometry).
// Phase 1: redundant prep a_h; gather channel row; min/max; histogram moments
//          (count,S1,S2,S3 per bin, f32 atomics) in LDS.
// Phase 1.5: pack moments to f16 (4 x f16 = 8B per bin) -> sweep LDS reads halve.
// Phase 2: each thread = one node tau_i; evaluates Phi(tau_i) = G/F via the
//          128-bin geometric-ladder sweep (2 ds_read_b128 per 4 bins).
__global__ __launch_bounds__(256) void k_tab(const float* __restrict__ x,
                                             const float* __restrict__ embed_w,
                                             const float* __restrict__ q_w,
                                             const float* __restrict__ k_w,
                                             float* __restrict__ ws) {
    __shared__ __align__(16) float M[NBIN][4];
    __shared__ __align__(16) __half2 Mp[NBIN * 2];   // 2 x __half2 per bin
    __shared__ float sh[2 * 256];
    __shared__ float em_s[DM];
    __shared__ float a_s[NH];
    __shared__ float redmax[4], redmin[4];

    const int bid = blockIdx.x, tid = threadIdx.x;
    const int n = bid >> 2, h = bid & 3;
    const int b = n >> 5, c = n & 31;

    // zero moments + load embed
    #pragma unroll
    for (int i = tid; i < NBIN * 4; i += 256) ((float*)M)[i] = 0.f;
    if (tid < DM) em_s[tid] = embed_w[tid];
    __syncthreads();

    // qv/kv partial sums (4-way split over e)
    {
        const int d = tid & 63, p = tid >> 6;
        float sq_ = 0.f, sk_ = 0.f;
        #pragma unroll
        for (int i = 0; i < 16; i++) {
            int e = p * 16 + i;
            float emv = em_s[e];
            sq_ = fmaf(q_w[d * DM + e], emv, sq_);
            sk_ = fmaf(k_w[d * DM + e], emv, sk_);
        }
        sh[tid] = sq_; sh[256 + tid] = sk_;
    }
    // gather this channel's 1024 values (strided, L2/L3-resident)
    const float* xp = x + b * (S_ * CH) + c;
    float v0 = xp[(tid * 4 + 0) * CH];
    float v1 = xp[(tid * 4 + 1) * CH];
    float v2 = xp[(tid * 4 + 2) * CH];
    float v3 = xp[(tid * 4 + 3) * CH];
    float lmax = fmaxf(fmaxf(v0, v1), fmaxf(v2, v3));
    float lmin = fminf(fminf(v0, v1), fminf(v2, v3));
    #pragma unroll
    for (int off = 32; off; off >>= 1) {
        lmax = fmaxf(lmax, __shfl_xor(lmax, off));
        lmin = fminf(lmin, __shfl_xor(lmin, off));
    }
    if ((tid & 63) == 0) { redmax[tid >> 6] = lmax; redmin[tid >> 6] = lmin; }
    __syncthreads();   // sh, red complete

    if (tid < NH) {
        float a = 0.f;
        #pragma unroll
        for (int i = 0; i < DH; i++) {
            int d = tid * DH + i;
            float qv = (sh[d] + sh[64 + d]) + (sh[128 + d] + sh[192 + d]);
            float kv = (sh[256 + d] + sh[320 + d]) + (sh[384 + d] + sh[448 + d]);
            a = fmaf(qv, kv, a);
        }
        a_s[tid] = a * 0.25f;   // 1/sqrt(16)
    }
    const float tmax = fmaxf(fmaxf(redmax[0], redmax[1]), fmaxf(redmax[2], redmax[3]));
    const float tmin = fminf(fminf(redmin[0], redmin[1]), fminf(redmin[2], redmin[3]));
    const float h_w  = (tmax - tmin) * (1.f / NBIN);
    const float b0   = tmin + 0.5f * h_w;
    const float binv = 1.f / h_w;

    // histogram moments (LDS atomics)
    const float vs[4] = {v0, v1, v2, v3};
    #pragma unroll
    for (int i = 0; i < 4; i++) {
        float t = vs[i];
        int k = (int)((t - tmin) * binv);
        k = k > (NBIN - 1) ? (NBIN - 1) : k;
        float d = t - fmaf((float)k, h_w, b0);
        atomicAdd(&M[k][0], 1.f);
        atomicAdd(&M[k][1], d);
        atomicAdd(&M[k][2], d * d);
        atomicAdd(&M[k][3], d * d * d);
    }
    __syncthreads();   // M, a_s complete

    // pack moments to f16: count exact (<2048), S1/S2/S3 are small corrections
    if (tid < NBIN) {
        float4 m = *(const float4*)&M[tid][0];
        Mp[tid * 2 + 0] = __floats2half2_rn(m.x, m.y);
        Mp[tid * 2 + 1] = __floats2half2_rn(m.z, m.w);
    }
    __syncthreads();

    // ---- node sweep: tau = tmin + tid * (range/255) ----
    const float dtau = (tmax - tmin) * (1.f / (NNODE - 1));
    const float tau  = fmaf((float)tid, dtau, tmin);
    const float cc   = tau * a_s[h];
    const float C1 = cc;
    const float C2 = cc * cc * 0.5f;
    const float C3 = C2 * cc * (1.f / 3.f);
    const float c2e = cc * L2E;
    const float bLast = fmaf((float)(NBIN - 1), h_w, b0);
    const float nm2 = -fmaxf(cc * b0, cc * bLast) * L2E;
    const float r4 = EXP2F(c2e * (4.f * h_w));

    const float4* Mp4 = (const float4*)Mp;   // one float4 = 2 bins (8 f16)
    float F0 = 0.f, F1 = 0.f, F2 = 0.f, F3 = 0.f;
    float G0 = 0.f, G1 = 0.f, G2 = 0.f, G3 = 0.f;
    #pragma unroll
    for (int chnk = 0; chnk < 4; chnk++) {
        const float bfb = fmaf((float)(chnk * 32), h_w, b0);
        float E0 = EXP2F(fmaf(c2e, bfb,             nm2));
        float E1 = EXP2F(fmaf(c2e, bfb + h_w,       nm2));
        float E2 = EXP2F(fmaf(c2e, bfb + 2.f * h_w, nm2));
        float E3 = EXP2F(fmaf(c2e, bfb + 3.f * h_w, nm2));
        #pragma unroll
        for (int t = 0; t < 8; t++) {
            const int kb = chnk * 32 + t * 4;          // 4 bins = 2 float4 reads
            float4 q0 = Mp4[(kb >> 1) + 0];
            float4 q1 = Mp4[(kb >> 1) + 1];
            const __half2* hp0 = (const __half2*)&q0;  // bins kb, kb+1
            const __half2* hp1 = (const __half2*)&q1;  // bins kb+2, kb+3
            const float n0 = __low2float(hp0[0]), s10 = __high2float(hp0[0]);
            const float s20 = __low2float(hp0[1]), s30 = __high2float(hp0[1]);
            const float n1 = __low2float(hp0[2]), s11 = __high2float(hp0[2]);
            const float s21 = __low2float(hp0[3]), s31 = __high2float(hp0[3]);
            const float n2 = __low2float(hp1[0]), s12 = __high2float(hp1[0]);
            const float s22 = __low2float(hp1[1]), s32 = __high2float(hp1[1]);
            const float n3 = __low2float(hp1[2]), s13 = __high2float(hp1[2]);
            const float s23 = __low2float(hp1[3]), s33 = __high2float(hp1[3]);
            const float bf0 = fmaf((float)(t * 4), h_w, bfb);
            const float bf1 = bf0 + h_w;
            const float bf2 = bf0 + 2.f * h_w;
            const float bf3 = bf0 + 3.f * h_w;
            float PF0 = fmaf(C3, s30, fmaf(C2, s20, fmaf(C1, s10, n0)));
            float PF1 = fmaf(C3, s31, fmaf(C2, s21, fmaf(C1, s11, n1)));
            float PF2 = fmaf(C3, s32, fmaf(C2, s22, fmaf(C1, s12, n2)));
            float PF3 = fmaf(C3, s33, fmaf(C2, s23, fmaf(C1, s13, n3)));
            float QG0 = fmaf(C2, s30, fmaf(C1, s20, s10));
            float QG1 = fmaf(C2, s31, fmaf(C1, s21, s11));
            float QG2 = fmaf(C2, s32, fmaf(C1, s22, s12));
            float QG3 = fmaf(C2, s33, fmaf(C1, s23, s13));
            F0 = fmaf(E0, PF0, F0);
            F1 = fmaf(E1, PF1, F1);
            F2 = fmaf(E2, PF2, F2);
            F3 = fmaf(E3, PF3, F3);
            G0 = fmaf(E0, fmaf(bf0, PF0, QG0), G0);
            G1 = fmaf(E1, fmaf(bf1, PF1, QG1), G1);
            G2 = fmaf(E2, fmaf(bf2, PF2, QG2), G2);
            G3 = fmaf(E3, fmaf(bf3, PF3, QG3), G3);
            E0 *= r4; E1 *= r4; E2 *= r4; E3 *= r4;
        }
    }
    const float F = (F0 + F1) + (F2 + F3);
    const float G = (G0 + G1) + (G2 + G3);
    ws[WS_T + (n * NH + h) * NNODE + tid] = G / F;
    if (tid == 0) {
        ws[WS_HDR + n * 4 + 0] = tmin;
        ws[WS_HDR + n * 4 + 1] = (float)(NNODE - 1) / (tmax - tmin);
    }
}

// ---------------------------------------------------------------------------
// K2: 128 blocks = (b 2) x (s-tile 64 of 16); 256 threads. (R12-identical)
__global__ __launch_bounds__(256) void k_fin(const float* __restrict__ ws,
                                             const float* __restrict__ x,
                                             const float* __restrict__ embed_w,
                                             const float* __restrict__ v_w,
                                             const float* __restrict__ o_w,
                                             const float* __restrict__ merge_w,
                                             float* __restrict__ out) {
    __shared__ float em_s[DM];
    __shared__ float sh[256];
    __shared__ float vv[DM];
    __shared__ float ov_s[256];
    __shared__ float part[4][4][16];
    __shared__ float W2[4][16];
    __shared__ float msh[32];
    __shared__ float hdr_s[CH][2];
    const int bid = blockIdx.x, tid = threadIdx.x;
    const int b  = bid >> 6;
    const int s0 = (bid & 63) * 16;

    if (tid < DM) em_s[tid] = embed_w[tid];
    if (tid >= 64 && tid < 128) {
        int c = (tid - 64) >> 1, j = tid & 1;
        hdr_s[c][j] = ws[WS_HDR + (b * CH + c) * 4 + j];
    }
    if (tid >= 128 && tid < 160) msh[tid - 128] = merge_w[tid - 128];
    __syncthreads();
    {
        const int d = tid & 63, p = tid >> 6;
        float sv = 0.f;
        #pragma unroll
        for (int i = 0; i < 16; i++) {
            int e = p * 16 + i;
            sv = fmaf(v_w[d * DM + e], em_s[e], sv);
        }
        sh[tid] = sv;
    }
    __syncthreads();
    if (tid < DM) vv[tid] = (sh[tid] + sh[64 + tid]) + (sh[128 + tid] + sh[192 + tid]);
    __syncthreads();
    {
        const int o = tid & 63, hh0 = tid >> 6;
        float s = 0.f;
        #pragma unroll
        for (int i = 0; i < DH; i++)
            s = fmaf(o_w[o * DM + hh0 * DH + i], vv[hh0 * DH + i], s);
        ov_s[o * NH + hh0] = s;
    }

    const int sl = tid & 15, h = (tid >> 4) & 3, cg_ = tid >> 6;
    float acc = 0.f;
    #pragma unroll
    for (int k = 0; k < 8; k++) {
        const int c = cg_ * 8 + k;
        const int n = b * CH + c;
        const float ts = x[(b * S_ + s0 + sl) * CH + c];
        const float u0 = (ts - hdr_s[c][0]) * hdr_s[c][1];
        const float u  = fminf(fmaxf(u0, 0.f), (float)(NNODE - 1));
        int i = (int)u;
        i = i > (NNODE - 2) ? (NNODE - 2) : i;
        const float f = u - (float)i;
        const float* T = ws + WS_T + (n * NH + h) * NNODE;
        const float t0 = T[i], t1 = T[i + 1];
        const float w = fmaf(f, t1 - t0, t0);
        acc = fmaf(msh[c], w, acc);
    }
    part[cg_][h][sl] = acc;
    __syncthreads();   // ov_s and part complete
    if (tid < 64) {
        int hh = tid >> 4, ss = tid & 15;
        W2[hh][ss] = (part[0][hh][ss] + part[1][hh][ss]) +
                     (part[2][hh][ss] + part[3][hh][ss]);
    }
    __syncthreads();
    #pragma unroll
    for (int rep = 0; rep < 4; rep++) {
        int idx = rep * 256 + tid;
        int o2 = idx & 63, ss = idx >> 6;
        float r = 0.f;
        #pragma unroll
        for (int hh = 0; hh < NH; hh++)
            r = fmaf(ov_s[o2 * NH + hh], W2[hh][ss], r);
        out[(b * S_ + s0 + ss) * COUT + o2] = r;
    }
}

extern "C" void kernel_launch(void* const* d_in, const int* in_sizes, int n_in,
                              void* d_out, int out_size, void* d_ws, size_t ws_size,
                              hipStream_t stream) {
    const float* x       = (const float*)d_in[0];
    const float* embed_w = (const float*)d_in[1];
    const float* q_w     = (const float*)d_in[2];
    const float* k_w     = (const float*)d_in[3];
    const float* v_w     = (const float*)d_in[4];
    const float* o_w     = (const float*)d_in[5];
    const float* merge_w = (const float*)d_in[6];
    float* ws  = (float*)d_ws;
    float* out = (float*)d_out;

    k_tab<<<256, 256, 0, stream>>>(x, embed_w, q_w, k_w, ws);
    k_fin<<<B_ * 64, 256, 0, stream>>>(ws, x, embed_w, v_w, o_w, merge_w, out);
}